// Round 1
// 505.324 us; speedup vs baseline: 1.1078x; 1.1078x over previous
//
#include <hip/hip_runtime.h>

// Problem constants (fixed by the reference's setup_inputs)
#define QS_ 512
#define B_  8
#define C_  1024
#define H_  16
#define HC_ 64
#define M_  1536
#define KS_ 512
#define VND 640    // padded new-V row: (L&7)+pad(512)+64+7 <= 583 < 640

typedef __attribute__((ext_vector_type(8))) short bf16x8;
typedef __attribute__((ext_vector_type(4))) float f32x4;

__device__ __forceinline__ short f2bf(float f) {
    unsigned u = __float_as_uint(f);
    unsigned r = (u + 0x7FFF + ((u >> 16) & 1)) >> 16;   // RNE
    return (short)r;
}

__device__ __forceinline__ void gload_lds16(const void* g, void* l) {
    __builtin_amdgcn_global_load_lds(
        (const __attribute__((address_space(1))) unsigned int*)g,
        (__attribute__((address_space(3))) unsigned int*)l, 16, 0, 0);
}

// ---------------------------------------------------------------------------
// f32 -> bf16 elementwise convert. 8 elems/thread.
// ---------------------------------------------------------------------------
__global__ __launch_bounds__(256) void cvt_f32_bf16(
    const float* __restrict__ src, short* __restrict__ dst, int n8)
{
    int i = blockIdx.x * 256 + threadIdx.x;
    if (i >= n8) return;
    const float4* s = (const float4*)src + (size_t)i * 2;
    float4 a = s[0], bq = s[1];
    short o[8];
    o[0] = f2bf(a.x);  o[1] = f2bf(a.y);  o[2] = f2bf(a.z);  o[3] = f2bf(a.w);
    o[4] = f2bf(bq.x); o[5] = f2bf(bq.y); o[6] = f2bf(bq.z); o[7] = f2bf(bq.w);
    *(uint4*)(dst + (size_t)i * 8) = *(uint4*)o;
}

// ---------------------------------------------------------------------------
// Fused convert of the four 1024x1024 weight matrices (one launch instead
// of four: saves ~3 launch overheads). idx>>17 selects the matrix.
// ---------------------------------------------------------------------------
__global__ __launch_bounds__(256) void cvt_w4(
    const float* __restrict__ w0, const float* __restrict__ w1,
    const float* __restrict__ w2, const float* __restrict__ w3,
    short* __restrict__ d0, short* __restrict__ d1,
    short* __restrict__ d2, short* __restrict__ d3)
{
    int idx = blockIdx.x * 256 + threadIdx.x;      // [0, 524288)
    int sel = idx >> 17;                           // 131072 = 2^17 per matrix
    int i = idx & 131071;
    const float* src = sel == 0 ? w0 : sel == 1 ? w1 : sel == 2 ? w2 : w3;
    short* dst = sel == 0 ? d0 : sel == 1 ? d1 : sel == 2 ? d2 : d3;
    const float4* s = (const float4*)src + (size_t)i * 2;
    float4 a = s[0], bq = s[1];
    short o[8];
    o[0] = f2bf(a.x);  o[1] = f2bf(a.y);  o[2] = f2bf(a.z);  o[3] = f2bf(a.w);
    o[4] = f2bf(bq.x); o[5] = f2bf(bq.y); o[6] = f2bf(bq.z); o[7] = f2bf(bq.w);
    *(uint4*)(dst + (size_t)i * 8) = *(uint4*)o;
}

// ---------------------------------------------------------------------------
// memory_kv [t][b][h][128] f32 -> K bf16 [b*H+h][t][64]  (direct)
//                              -> V bf16 [b*H+h][hc][1536] (LDS transpose)
// Block = (t-chunk 64, h, b).
// ---------------------------------------------------------------------------
__global__ __launch_bounds__(256) void mkv_prep(
    const float* __restrict__ mkv, short* __restrict__ kOut,
    short* __restrict__ vOut)
{
    __shared__ short T[64][72];
    const int tc = blockIdx.x, h = blockIdx.y, b = blockIdx.z;
    const int tid = threadIdx.x;
    const int row = tid >> 2, part = tid & 3;
    const int t = tc * 64 + row;
    const int g = b * H_ + h;
    const float4* src = (const float4*)(mkv + (((size_t)t * B_ + b) * H_ + h) * 128 + part * 32);
    short o[32];
#pragma unroll
    for (int j = 0; j < 8; ++j) {
        float4 f = src[j];
        o[j * 4 + 0] = f2bf(f.x); o[j * 4 + 1] = f2bf(f.y);
        o[j * 4 + 2] = f2bf(f.z); o[j * 4 + 3] = f2bf(f.w);
    }
    if (part < 2) {   // K half: cols 0..63
        short* d = kOut + ((size_t)g * M_ + t) * 64 + part * 32;
#pragma unroll
        for (int j = 0; j < 4; ++j) ((uint4*)d)[j] = ((uint4*)o)[j];
    } else {          // V half: cols 64..127 -> transpose via LDS
        int hc0 = (part - 2) * 32;
#pragma unroll
        for (int j = 0; j < 32; ++j) T[hc0 + j][row] = o[j];
    }
    __syncthreads();
    const int hc = tid >> 2, seg = tid & 3;
    uint4 a = *(const uint4*)&T[hc][seg * 16];
    uint4 c = *(const uint4*)&T[hc][seg * 16 + 8];
    short* d = vOut + ((size_t)g * HC_ + hc) * M_ + tc * 64 + seg * 16;
    ((uint4*)d)[0] = a; ((uint4*)d)[1] = c;
}

// ---------------------------------------------------------------------------
// vbuf [s][b][C] bf16 -> vnewT [b*H+h][hc][VND] at column (L&7)+s
// (absolute-t-aligned so attention V-fragment loads stay 16B aligned).
// Block = (s-chunk 64, h, b).
// ---------------------------------------------------------------------------
__global__ __launch_bounds__(256) void v_transpose(
    const short* __restrict__ vbuf, const int* __restrict__ mlen,
    short* __restrict__ vOut)
{
    __shared__ short T[64][72];
    const int sc = blockIdx.x, h = blockIdx.y, b = blockIdx.z;
    const int tid = threadIdx.x;
    const int r = tid >> 2, seg = tid & 3;
    const int s = sc * 64 + r;
    const short* src = vbuf + ((size_t)s * B_ + b) * C_ + h * HC_ + seg * 16;
    short tmp[16];
    *(uint4*)&tmp[0] = ((const uint4*)src)[0];
    *(uint4*)&tmp[8] = ((const uint4*)src)[1];
#pragma unroll
    for (int j = 0; j < 16; ++j) T[seg * 16 + j][r] = tmp[j];
    __syncthreads();
    const int L7 = mlen[b] & 7;
    const int hc = tid >> 2;
    const int g = b * H_ + h;
    short* drow = vOut + ((size_t)g * HC_ + hc) * VND + L7 + sc * 64 + seg * 16;
    const short* srow = &T[hc][seg * 16];
#pragma unroll
    for (int j = 0; j < 16; ++j) drow[j] = srow[j];   // scalar: dst may be odd-aligned
}

// ---------------------------------------------------------------------------
// m97-style bf16 NT GEMM body: 128x128 tile, BK=64, global_load_lds width-16,
// 4 waves each 64x64 quadrant (4x4 16x16x32 tiles).
// ---------------------------------------------------------------------------
template <bool BF16OUT>
__device__ __forceinline__ void gemm128_body(
    short (*As)[64], short (*Ws)[64],
    const short* __restrict__ A, const short* __restrict__ W,
    const float* __restrict__ bias, void* __restrict__ outv,
    int n0, int j0)
{
    const int tid  = threadIdx.x;
    const int lane = tid & 63;
    const int wave = tid >> 6;
    const int wm = (wave & 1) * 64;
    const int wn = (wave >> 1) * 64;
    const int lr = lane & 15;
    const int quad = lane >> 4;

    f32x4 acc[4][4];
#pragma unroll
    for (int i = 0; i < 4; ++i)
#pragma unroll
        for (int j = 0; j < 4; ++j)
            acc[i][j] = (f32x4){0.f, 0.f, 0.f, 0.f};

    for (int k0 = 0; k0 < C_; k0 += 64) {
#pragma unroll
        for (int p = 0; p < 4; ++p) {
            int flat = p * 256 + tid;
            int r = flat >> 3, c8 = (flat & 7) * 8;
            gload_lds16(A + (size_t)(n0 + r) * C_ + k0 + c8, (short*)As + flat * 8);
        }
#pragma unroll
        for (int p = 0; p < 4; ++p) {
            int flat = p * 256 + tid;
            int r = flat >> 3, c8 = (flat & 7) * 8;
            gload_lds16(W + (size_t)(j0 + r) * C_ + k0 + c8, (short*)Ws + flat * 8);
        }
        __syncthreads();
#pragma unroll
        for (int ks = 0; ks < 2; ++ks) {
            const int kk = ks * 32 + quad * 8;
            bf16x8 afrag[4], bfrag[4];
#pragma unroll
            for (int im = 0; im < 4; ++im)
                afrag[im] = *(const bf16x8*)&As[wm + im * 16 + lr][kk];
#pragma unroll
            for (int jn = 0; jn < 4; ++jn)
                bfrag[jn] = *(const bf16x8*)&Ws[wn + jn * 16 + lr][kk];
#pragma unroll
            for (int im = 0; im < 4; ++im)
#pragma unroll
                for (int jn = 0; jn < 4; ++jn)
                    acc[im][jn] = __builtin_amdgcn_mfma_f32_16x16x32_bf16(
                        afrag[im], bfrag[jn], acc[im][jn], 0, 0, 0);
        }
        __syncthreads();
    }

#pragma unroll
    for (int jn = 0; jn < 4; ++jn) {
        const int col = j0 + wn + jn * 16 + lr;
        const float bv = bias[col];
#pragma unroll
        for (int im = 0; im < 4; ++im) {
            const int row = n0 + wm + im * 16 + quad * 4;
#pragma unroll
            for (int r = 0; r < 4; ++r) {
                float v = acc[im][jn][r] + bv;
                if (BF16OUT)
                    ((short*)outv)[(size_t)(row + r) * C_ + col] = f2bf(v);
                else
                    ((float*)outv)[(size_t)(row + r) * C_ + col] = v;
            }
        }
    }
}

template <bool BF16OUT>
__global__ __launch_bounds__(256) void gemm128(
    const short* __restrict__ A, const short* __restrict__ W,
    const float* __restrict__ bias, void* __restrict__ outv)
{
    __shared__ short As[128][64];
    __shared__ short Ws[128][64];
    gemm128_body<BF16OUT>(As, Ws, A, W, bias, outv,
                          blockIdx.x * 128, blockIdx.y * 128);
}

// Fused Q/K/V projection: grid (32, 24). blockIdx.y>>3 selects which of the
// three GEMMs; 768 blocks = 3 blocks/CU resident concurrently (vs 1 for a
// single 256-block GEMM) -> latency hiding via inter-block TLP.
__global__ __launch_bounds__(256) void gemm128_qkv(
    const short* __restrict__ A,
    const short* __restrict__ Wq, const short* __restrict__ Wk,
    const short* __restrict__ Wv,
    const float* __restrict__ bq, const float* __restrict__ bk,
    const float* __restrict__ bv,
    short* __restrict__ oq, short* __restrict__ ok, short* __restrict__ ov)
{
    __shared__ short As[128][64];
    __shared__ short Ws[128][64];
    const int sel = blockIdx.y >> 3;
    const short* W   = sel == 0 ? Wq : sel == 1 ? Wk : Wv;
    const float* bia = sel == 0 ? bq : sel == 1 ? bk : bv;
    short* out       = sel == 0 ? oq : sel == 1 ? ok : ov;
    gemm128_body<true>(As, Ws, A, W, bia, out,
                       blockIdx.x * 128, (blockIdx.y & 7) * 128);
}

// ---------------------------------------------------------------------------
// Flash attention, t-split ("flash-decoding") version.
// Block = one (b,h,q-group of 16). Its 4 waves each process a contiguous
// quarter of the t-chunk range with private online-softmax state (m,l,O);
// the partials are combined once through LDS at block end. No barrier inside
// the t-loop (waves have different trip counts). Grid 4096 blocks (4x the
// old wave-level parallelism; smooths the per-b tend imbalance tail).
// bx&127 = g keeps g%8 == bx%8 -> same-(b,h) K/V stream stays on one XCD L2.
// ---------------------------------------------------------------------------
__global__ __launch_bounds__(256) void attn_wave(
    const short* __restrict__ qb, const short* __restrict__ kbuf,
    const short* __restrict__ kmem, const short* __restrict__ vmem,
    const short* __restrict__ vnew, const int* __restrict__ mlen,
    const int* __restrict__ padv, const unsigned char* __restrict__ maskb,
    short* __restrict__ xout)
{
    __shared__ float Osh[4][64][17];   // [wave][hc][q], +1 pad
    __shared__ float msh[4][16];
    __shared__ float lsh[4][16];

    const int tid  = threadIdx.x;
    const int lane = tid & 63;
    const int wave = tid >> 6;
    const int lr   = lane & 15;
    const int quad = lane >> 4;
    const int bx = blockIdx.x;
    const int g = bx & 127;            // b*16+h
    const int b = g >> 4, h = g & 15;
    const int s0 = (bx >> 7) * 16;     // q-group base (32 groups)
    const int L = mlen[b], P = padv[b];
    const int tend = L + P;
    const int Lbase = L & ~7;
    const float NEG = -1e30f;

    // Q fragments (persistent; redundantly loaded by the 4 waves - tiny)
    const short* qrow = qb + ((size_t)(s0 + lr) * B_ + b) * C_ + h * HC_;
    bf16x8 q0 = *(const bf16x8*)(qrow + quad * 8);
    bf16x8 q1 = *(const bf16x8*)(qrow + 32 + quad * 8);

    const short* kmb = kmem + (size_t)g * M_ * 64 + quad * 8;
    const short* knb = kbuf + (size_t)b * C_ + h * HC_ + quad * 8;   // + s*(B_*C_)
    const short* vmb = vmem + (size_t)g * HC_ * M_;
    const short* vnb = vnew + (size_t)g * HC_ * VND;
    const int q = s0 + lr;

    f32x4 O[4];
#pragma unroll
    for (int i = 0; i < 4; ++i) O[i] = (f32x4){0.f, 0.f, 0.f, 0.f};
    float mr = NEG, lsum = 0.f;

    const int nch = (tend + 63) >> 6;
    const int cpw = (nch + 3) >> 2;            // chunks per wave
    const int c0 = wave * cpw;
    const int c1 = min(nch, c0 + cpw);
    for (int ci = c0; ci < c1; ++ci) {
        const int t0 = ci << 6;

        // ---- K fragments: A[m=t(lr)][k=hc(quad*8+j)] ----
        bf16x8 kf[4][2];
#pragma unroll
        for (int tt = 0; tt < 4; ++tt) {
            int t = t0 + tt * 16 + lr;
            const short* p = (t < L)
                ? (kmb + (size_t)t * 64)
                : (knb + (size_t)min(t - L, KS_ - 1) * (B_ * C_));
            kf[tt][0] = *(const bf16x8*)p;
            kf[tt][1] = *(const bf16x8*)(p + 32);
        }

        // ---- S^T = K . Q^T ----
        f32x4 S[4];
#pragma unroll
        for (int tt = 0; tt < 4; ++tt) {
            f32x4 z = (f32x4){0.f, 0.f, 0.f, 0.f};
            z = __builtin_amdgcn_mfma_f32_16x16x32_bf16(kf[tt][0], q0, z, 0, 0, 0);
            S[tt] = __builtin_amdgcn_mfma_f32_16x16x32_bf16(kf[tt][1], q1, z, 0, 0, 0);
        }

        // ---- V fragments (issued now; waited at PV): A[m=hc(lr)][k=t] ----
        bf16x8 vf[4][2];
        const bool slowV = (L > t0) && (L < t0 + 64) && ((L & 7) != 0);
        if (!slowV) {
#pragma unroll
            for (int hf = 0; hf < 2; ++hf) {
                int tf = t0 + hf * 32 + quad * 8;
                bool inmem = tf < L;
#pragma unroll
                for (int ht = 0; ht < 4; ++ht) {
                    int hc = ht * 16 + lr;
                    const short* p = inmem ? (vmb + (size_t)hc * M_ + tf)
                                           : (vnb + (size_t)hc * VND + (tf - Lbase));
                    vf[ht][hf] = *(const bf16x8*)p;
                }
            }
        } else {  // chunk straddles L at non-8-aligned boundary (rare, wave-uniform)
#pragma unroll
            for (int hf = 0; hf < 2; ++hf)
#pragma unroll
                for (int ht = 0; ht < 4; ++ht) {
                    short tmp[8];
                    int hc = ht * 16 + lr;
#pragma unroll
                    for (int j = 0; j < 8; ++j) {
                        int t = t0 + hf * 32 + quad * 8 + j;
                        tmp[j] = (t < L) ? vmb[(size_t)hc * M_ + t]
                                         : vnb[(size_t)hc * VND + (t - Lbase)];
                    }
                    vf[ht][hf] = *(const bf16x8*)tmp;
                }
        }

        // ---- mask + scale; lane value (tt,r) is (q=lr, t=t0+tt*16+quad*4+r) ----
        float p4[4][4];
        const bool anyNew = (t0 + 63 >= L);
#pragma unroll
        for (int tt = 0; tt < 4; ++tt)
#pragma unroll
            for (int r = 0; r < 4; ++r) {
                float val = S[tt][r] * 0.125f;
                if (anyNew) {
                    int t = t0 + tt * 16 + quad * 4 + r;
                    if (t >= L) {
                        int off = t - L;
                        bool masked = true;
                        if (off < P)
                            masked = (maskb[((size_t)q * KS_ + off) * B_ + b] != 0);
                        if (masked) val = NEG;
                    }
                }
                p4[tt][r] = val;
            }

        // ---- online softmax for q=lr (reduce across quads: xor 16,32) ----
        float rm = NEG;
#pragma unroll
        for (int tt = 0; tt < 4; ++tt)
#pragma unroll
            for (int r = 0; r < 4; ++r) rm = fmaxf(rm, p4[tt][r]);
        rm = fmaxf(rm, __shfl_xor(rm, 16, 64));
        rm = fmaxf(rm, __shfl_xor(rm, 32, 64));
        float nm = fmaxf(mr, rm);
        float al = __expf(mr - nm);
        float rs = 0.f;
#pragma unroll
        for (int tt = 0; tt < 4; ++tt)
#pragma unroll
            for (int r = 0; r < 4; ++r) {
                float e = (p4[tt][r] == NEG) ? 0.f : __expf(p4[tt][r] - nm);
                p4[tt][r] = e;
                rs += e;
            }
        rs += __shfl_xor(rs, 16, 64);
        rs += __shfl_xor(rs, 32, 64);
        lsum = lsum * al + rs;
        mr = nm;
#pragma unroll
        for (int ht = 0; ht < 4; ++ht)
#pragma unroll
            for (int r = 0; r < 4; ++r) O[ht][r] *= al;

        // ---- P^T fragments via in-wave shuffles:
        //      B[n=q(lr)][k=t(quad*8+j)] from C-layout S^T tiles ----
        bf16x8 pf[2];
#pragma unroll
        for (int hf = 0; hf < 2; ++hf) {
            const int tt0 = hf * 2;
            const int slA = ((quad & 1) * 2) * 16 + lr;
            const int slB = slA + 16;
            const bool hi = (quad & 2) != 0;
            short fr[8];
#pragma unroll
            for (int r = 0; r < 4; ++r) {
                float a0 = __shfl(p4[tt0][r],     slA, 64);
                float a1 = __shfl(p4[tt0 + 1][r], slA, 64);
                float b0 = __shfl(p4[tt0][r],     slB, 64);
                float b1 = __shfl(p4[tt0 + 1][r], slB, 64);
                fr[r]     = f2bf(hi ? a1 : a0);
                fr[4 + r] = f2bf(hi ? b1 : b0);
            }
            pf[hf] = *(const bf16x8*)fr;
        }

        // ---- O^T += V^T . P^T ----
#pragma unroll
        for (int ht = 0; ht < 4; ++ht) {
            O[ht] = __builtin_amdgcn_mfma_f32_16x16x32_bf16(vf[ht][0], pf[0], O[ht], 0, 0, 0);
            O[ht] = __builtin_amdgcn_mfma_f32_16x16x32_bf16(vf[ht][1], pf[1], O[ht], 0, 0, 0);
        }
    }

    // ---- write per-wave partials (unnormalized O, m, l) ----
#pragma unroll
    for (int ht = 0; ht < 4; ++ht)
#pragma unroll
        for (int r = 0; r < 4; ++r)
            Osh[wave][ht * 16 + quad * 4 + r][lr] = O[ht][r];
    if (quad == 0) { msh[wave][lr] = mr; lsh[wave][lr] = lsum; }
    __syncthreads();

    // ---- combine 4 partials: thread -> (q = tid>>4, hc block = (tid&15)*4) ----
    const int qq  = tid >> 4;
    const int hc0 = (tid & 15) * 4;
    float m0 = msh[0][qq], m1 = msh[1][qq], m2 = msh[2][qq], m3 = msh[3][qq];
    float M = fmaxf(fmaxf(m0, m1), fmaxf(m2, m3));
    float s0f = __expf(m0 - M), s1f = __expf(m1 - M);
    float s2f = __expf(m2 - M), s3f = __expf(m3 - M);
    float l = lsh[0][qq] * s0f + lsh[1][qq] * s1f
            + lsh[2][qq] * s2f + lsh[3][qq] * s3f;
    float inv = (l > 0.f) ? 1.0f / l : 0.f;
    short ov[4];
#pragma unroll
    for (int j = 0; j < 4; ++j) {
        float val = Osh[0][hc0 + j][qq] * s0f + Osh[1][hc0 + j][qq] * s1f
                  + Osh[2][hc0 + j][qq] * s2f + Osh[3][hc0 + j][qq] * s3f;
        ov[j] = f2bf(val * inv);
    }
    short* d = xout + ((size_t)(s0 + qq) * B_ + b) * C_ + h * HC_ + hc0;
    *(long long*)d = *(const long long*)ov;
}

// ---------------------------------------------------------------------------
extern "C" void kernel_launch(void* const* d_in, const int* in_sizes, int n_in,
                              void* d_out, int out_size, void* d_ws, size_t ws_size,
                              hipStream_t stream)
{
    const float* xq   = (const float*)d_in[0];
    const int*   pad  = (const int*)d_in[1];
    const unsigned char* maskb = (const unsigned char*)d_in[2];
    const int*   mlen = (const int*)d_in[3];
    const float* mkv  = (const float*)d_in[4];
    const float* Wq   = (const float*)d_in[5];
    const float* bq   = (const float*)d_in[6];
    const float* Wk   = (const float*)d_in[7];
    const float* bk   = (const float*)d_in[8];
    const float* Wv   = (const float*)d_in[9];
    const float* bv   = (const float*)d_in[10];
    const float* Wo   = (const float*)d_in[11];
    const float* bo   = (const float*)d_in[12];
    float* out = (float*)d_out;

    // Workspace layout (shorts), ~120 MiB
    short* xqb  = (short*)d_ws;
    short* wqb  = xqb  + (size_t)4194304;                 // 512*8*1024
    short* wkb  = wqb  + (size_t)1048576;
    short* wvb  = wkb  + (size_t)1048576;
    short* wob  = wvb  + (size_t)1048576;
    short* kmem = wob  + (size_t)1048576;                 // 128*1536*64 = 12.58M
    short* vmem = kmem + (size_t)128 * M_ * 64;           // 128*64*1536 = 12.58M
    short* vnew = vmem + (size_t)128 * HC_ * M_;          // 128*64*640  = 5.24M
    short* qbuf = vnew + (size_t)128 * HC_ * VND;
    short* kbuf = qbuf + (size_t)4194304;
    short* vbuf = kbuf + (size_t)4194304;
    short* xbuf = vbuf + (size_t)4194304;

    dim3 gblk(256);
    // 1) bf16 pre-conversions + memory_kv prep (K direct, V transposed)
    cvt_f32_bf16<<<dim3(2048), gblk, 0, stream>>>(xq, xqb, 524288);
    cvt_w4<<<dim3(2048), gblk, 0, stream>>>(Wq, Wk, Wv, Wo, wqb, wkb, wvb, wob);
    mkv_prep<<<dim3(24, 16, 8), gblk, 0, stream>>>(mkv, kmem, vmem);

    // 2) fused q/k/v projection (bf16 out), 768 blocks
    gemm128_qkv<<<dim3(32, 24), gblk, 0, stream>>>(
        xqb, wqb, wkb, wvb, bq, bk, bv, qbuf, kbuf, vbuf);
    v_transpose<<<dim3(8, 16, 8), gblk, 0, stream>>>(vbuf, mlen, vnew);

    // 3) t-split flash attention + in-block combine
    attn_wave<<<dim3(4096), gblk, 0, stream>>>(qbuf, kbuf, kmem, vmem, vnew,
                                               mlen, pad, maskb, xbuf);

    // 4) output projection (f32 out)
    gemm128<false><<<dim3(32, 8), gblk, 0, stream>>>(xbuf, wob, bo, out);
}